// Round 1
// baseline (105.517 us; speedup 1.0000x reference)
//
#include <hip/hip_runtime.h>
#include <stdint.h>

#define NN 2048
#define KK 20
#define NSLICE 8   // L*B = 2*4

// Kernel 1: one 64-lane wave per row. Each lane holds 32 scores in registers.
// Finds the exact ordered top-20 (score desc, index asc on ties) per row,
// writes base output adj*EPS, and sets flags[slice][col][rank]=1.
__global__ __launch_bounds__(256) void mask_topk_rows(
    const float* __restrict__ adj, const float* __restrict__ noise,
    float* __restrict__ out, unsigned char* __restrict__ flags)
{
    const int lane  = threadIdx.x & 63;
    const int wave  = threadIdx.x >> 6;
    const int row_g = (blockIdx.x << 2) + wave;     // 0..16383
    const int slice = row_g >> 11;                  // /2048
    const int row   = row_g & (NN - 1);
    const size_t base = ((size_t)slice * NN + row) * NN;
    const float* __restrict__ arow = adj + base;
    const float* __restrict__ nrow = noise + base;
    float* __restrict__ orow = out + base;

    float sc[32];
    unsigned long long m1 = 0ull, m2 = 0ull;   // per-lane top-2 keys
    const int lane4 = lane << 2;

    #pragma unroll
    for (int t = 0; t < 8; ++t) {
        const int col = t * 256 + lane4;
        const float4 av = *reinterpret_cast<const float4*>(arow + col);
        const float4 nv = *reinterpret_cast<const float4*>(nrow + col);
        float4 ov;
        ov.x = av.x * 1e-7f; ov.y = av.y * 1e-7f;
        ov.z = av.z * 1e-7f; ov.w = av.w * 1e-7f;
        *reinterpret_cast<float4*>(orow + col) = ov;
        float s[4];
        {
            // must match numpy bitwise: separate mul + add, NO fma contraction
            #pragma clang fp contract(off)
            s[0] = fabsf(av.x) + nv.x * 0.01f;
            s[1] = fabsf(av.y) + nv.y * 0.01f;
            s[2] = fabsf(av.z) + nv.z * 0.01f;
            s[3] = fabsf(av.w) + nv.w * 0.01f;
        }
        #pragma unroll
        for (int c = 0; c < 4; ++c) {
            sc[t * 4 + c] = s[c];
            // score >= 0 always, so float bits compare monotonically as uint.
            // low 32 bits: 2047-col -> on equal score, larger key = smaller col.
            unsigned long long k =
                ((unsigned long long)__float_as_uint(s[c]) << 32) |
                (unsigned int)(NN - 1 - (col + c));
            if (k > m1) { m2 = m1; m1 = k; }
            else if (k > m2) { m2 = k; }
        }
    }

    bool m2v = true;
    unsigned int removed = 0;
    unsigned int mycol = 0;

    #pragma clang loop unroll(disable)
    for (int pass = 0; pass < KK; ++pass) {
        // 64-lane butterfly max on the 64-bit key
        unsigned long long g = m1;
        #pragma unroll
        for (int d = 1; d < 64; d <<= 1) {
            unsigned long long o = __shfl_xor(g, d, 64);
            if (o > g) g = o;
        }
        const unsigned int col = (NN - 1) - (unsigned int)(g & 0xffffffffu);
        if (lane == pass) mycol = col;        // lane `pass` remembers rank-`pass` col
        if (m1 == g) {                        // unique owner (keys distinct)
            const int slot = ((col >> 8) << 2) | (col & 3);
            removed |= (1u << slot);
            if (m2v) { m1 = m2; m2 = 0ull; m2v = false; }
            else {
                // rare: this lane won twice since last rescan -> rebuild top-2
                m1 = 0ull; m2 = 0ull;
                #pragma unroll
                for (int ss = 0; ss < 32; ++ss) {
                    if (!((removed >> ss) & 1u)) {
                        const int c2 = ((ss >> 2) << 8) + lane4 + (ss & 3);
                        unsigned long long k =
                            ((unsigned long long)__float_as_uint(sc[ss]) << 32) |
                            (unsigned int)(NN - 1 - c2);
                        if (k > m1) { m2 = m1; m1 = k; }
                        else if (k > m2) { m2 = k; }
                    }
                }
                m2v = true;
            }
        }
    }

    if (lane < KK) {
        // flags[slice][mycol][rank] = 1; races write the same value -> benign
        flags[((size_t)slice * NN + mycol) * KK + lane] = 1;
    }
}

// Kernel 2: boost flagged entries out[slice][c][j] = adj*(1+EPS), j<20
__global__ __launch_bounds__(256) void mask_boost(
    const float* __restrict__ adj, float* __restrict__ out,
    const unsigned char* __restrict__ flags)
{
    const int idx = blockIdx.x * 256 + threadIdx.x;
    if (idx >= NSLICE * NN * KK) return;
    if (flags[idx]) {
        const int j = idx % KK;
        const int c = (idx / KK) & (NN - 1);
        const int slice = idx / (KK * NN);
        const size_t off = ((size_t)slice * NN + c) * NN + j;
        out[off] = adj[off] * (1.0f + 1e-7f);
    }
}

extern "C" void kernel_launch(void* const* d_in, const int* in_sizes, int n_in,
                              void* d_out, int out_size, void* d_ws, size_t ws_size,
                              hipStream_t stream) {
    const float* adj   = (const float*)d_in[0];
    const float* noise = (const float*)d_in[1];
    float* out = (float*)d_out;
    unsigned char* flags = (unsigned char*)d_ws;
    const size_t flag_bytes = (size_t)NSLICE * NN * KK;  // 327,680 B

    hipMemsetAsync(d_ws, 0, flag_bytes, stream);

    const int rows = NSLICE * NN;                 // 16384 rows, 4 per block
    mask_topk_rows<<<rows / 4, 256, 0, stream>>>(adj, noise, out, flags);

    const int total = NSLICE * NN * KK;
    mask_boost<<<(total + 255) / 256, 256, 0, stream>>>(adj, out, flags);
}

// Round 2
// 93.482 us; speedup vs baseline: 1.1287x; 1.1287x over previous
//
#include <hip/hip_runtime.h>
#include <stdint.h>

#define NN 2048
#define KK 20
#define NSLICE 8   // L*B = 2*4

// Wave-wide max of a nonnegative int, broadcast to all lanes via SGPR.
// Pure VALU (DPP) + 1 readlane -- zero LDS/DS traffic, ~30cy dependent latency.
__device__ __forceinline__ int wave_max_i32(int v) {
    int t;
    t = __builtin_amdgcn_update_dpp(0, v, 0x111, 0xf, 0xf, true);  // row_shr:1
    v = (v > t) ? v : t;
    t = __builtin_amdgcn_update_dpp(0, v, 0x112, 0xf, 0xf, true);  // row_shr:2
    v = (v > t) ? v : t;
    t = __builtin_amdgcn_update_dpp(0, v, 0x114, 0xf, 0xf, true);  // row_shr:4
    v = (v > t) ? v : t;
    t = __builtin_amdgcn_update_dpp(0, v, 0x118, 0xf, 0xf, true);  // row_shr:8
    v = (v > t) ? v : t;
    t = __builtin_amdgcn_update_dpp(v, v, 0x142, 0xa, 0xf, false); // row_bcast:15
    v = (v > t) ? v : t;
    t = __builtin_amdgcn_update_dpp(v, v, 0x143, 0xc, 0xf, false); // row_bcast:31
    v = (v > t) ? v : t;
    return __builtin_amdgcn_readlane(v, 63);
}

// Kernel 1: one 64-lane wave per row; 32 scores/lane in registers.
// Exact ordered top-20 (score desc, index asc) per row; writes base output
// adj*EPS and winners[slice][row][rank] = col (always written, no memset).
__global__ __launch_bounds__(256) void mask_topk_rows(
    const float* __restrict__ adj, const float* __restrict__ noise,
    float* __restrict__ out, unsigned short* __restrict__ winners)
{
    const int lane  = threadIdx.x & 63;
    const int wave  = threadIdx.x >> 6;
    const int row_g = (blockIdx.x << 2) + wave;     // 0..16383
    const int slice = row_g >> 11;
    const int row   = row_g & (NN - 1);
    const size_t base = ((size_t)slice * NN + row) * NN;
    const float* __restrict__ arow = adj + base;
    const float* __restrict__ nrow = noise + base;
    float* __restrict__ orow = out + base;

    float sc[32];
    unsigned long long m1 = 0ull, m2 = 0ull;   // per-lane top-2 keys
    const int lane4 = lane << 2;

    #pragma unroll
    for (int t = 0; t < 8; ++t) {
        const int col = t * 256 + lane4;
        const float4 av = *reinterpret_cast<const float4*>(arow + col);
        const float4 nv = *reinterpret_cast<const float4*>(nrow + col);
        float4 ov;
        ov.x = av.x * 1e-7f; ov.y = av.y * 1e-7f;
        ov.z = av.z * 1e-7f; ov.w = av.w * 1e-7f;
        *reinterpret_cast<float4*>(orow + col) = ov;
        float s[4];
        {
            // must match numpy bitwise: separate mul + add, NO fma contraction
            #pragma clang fp contract(off)
            s[0] = fabsf(av.x) + nv.x * 0.01f;
            s[1] = fabsf(av.y) + nv.y * 0.01f;
            s[2] = fabsf(av.z) + nv.z * 0.01f;
            s[3] = fabsf(av.w) + nv.w * 0.01f;
        }
        #pragma unroll
        for (int c = 0; c < 4; ++c) {
            sc[t * 4 + c] = s[c];
            // score >= 0 -> float bits compare monotonically as int (<2^31).
            // low 32: 2047-col -> equal score: larger key = smaller col.
            unsigned long long k =
                ((unsigned long long)__float_as_uint(s[c]) << 32) |
                (unsigned int)(NN - 1 - (col + c));
            if (k > m1) { m2 = m1; m1 = k; }
            else if (k > m2) { m2 = k; }
        }
    }

    bool m2v = true;
    unsigned int removed = 0;
    unsigned int mycol = 0;

    #pragma clang loop unroll(disable)
    for (int pass = 0; pass < KK; ++pass) {
        const int hs = (int)(unsigned)(m1 >> 32);         // score bits
        const int smax = wave_max_i32(hs);                // global max score
        const bool tied = (hs == smax);
        const int lo = (int)(unsigned)(m1 & 0xffffffffu); // 2047-col
        const int tmax = wave_max_i32(tied ? lo : 0);     // best tiebreak among tied
        const unsigned int col = (NN - 1) - (unsigned int)tmax;
        if (lane == pass) mycol = col;
        if (tied && lo == tmax) {                         // unique winner lane
            const int slot = ((col >> 8) << 2) | (col & 3);
            removed |= (1u << slot);
            if (m2v) { m1 = m2; m2 = 0ull; m2v = false; }
            else {
                // this lane won twice since last rescan -> rebuild top-2
                m1 = 0ull; m2 = 0ull;
                #pragma unroll
                for (int ss = 0; ss < 32; ++ss) {
                    if (!((removed >> ss) & 1u)) {
                        const int c2 = ((ss >> 2) << 8) + lane4 + (ss & 3);
                        unsigned long long k =
                            ((unsigned long long)__float_as_uint(sc[ss]) << 32) |
                            (unsigned int)(NN - 1 - c2);
                        if (k > m1) { m2 = m1; m1 = k; }
                        else if (k > m2) { m2 = k; }
                    }
                }
                m2v = true;
            }
        }
    }

    if (lane < KK) {
        winners[((size_t)slice * NN + row) * KK + lane] = (unsigned short)mycol;
    }
}

// Kernel 2: for each (slice,row,rank): col = winners[...];
// out[slice][col][rank] = adj*(1+EPS). Duplicate (col,rank) across rows
// write identical values -> benign race.
__global__ __launch_bounds__(256) void mask_boost(
    const float* __restrict__ adj, float* __restrict__ out,
    const unsigned short* __restrict__ winners)
{
    const int idx = blockIdx.x * 256 + threadIdx.x;
    if (idx >= NSLICE * NN * KK) return;
    const int rank  = idx % KK;
    const int slice = idx / (KK * NN);
    const int col = winners[idx];
    const size_t off = ((size_t)slice * NN + col) * NN + rank;
    out[off] = adj[off] * (1.0f + 1e-7f);
}

extern "C" void kernel_launch(void* const* d_in, const int* in_sizes, int n_in,
                              void* d_out, int out_size, void* d_ws, size_t ws_size,
                              hipStream_t stream) {
    const float* adj   = (const float*)d_in[0];
    const float* noise = (const float*)d_in[1];
    float* out = (float*)d_out;
    unsigned short* winners = (unsigned short*)d_ws;  // 8*2048*20*2B = 640 KiB

    const int rows = NSLICE * NN;                 // 16384 rows, 4 per block
    mask_topk_rows<<<rows / 4, 256, 0, stream>>>(adj, noise, out, winners);

    const int total = NSLICE * NN * KK;           // 327,680
    mask_boost<<<(total + 255) / 256, 256, 0, stream>>>(adj, out, winners);
}

// Round 3
// 80.989 us; speedup vs baseline: 1.3029x; 1.1543x over previous
//
#include <hip/hip_runtime.h>
#include <stdint.h>

#define NN 2048
#define KK 20
#define NSLICE 8   // L*B = 2*4

typedef float vfloat4 __attribute__((ext_vector_type(4)));

// Wave-wide max of a nonnegative int, result broadcast (SGPR). Pure VALU DPP.
__device__ __forceinline__ int wave_max_i32(int v) {
    int t;
    t = __builtin_amdgcn_update_dpp(0, v, 0x111, 0xf, 0xf, true);  // row_shr:1
    v = (v > t) ? v : t;
    t = __builtin_amdgcn_update_dpp(0, v, 0x112, 0xf, 0xf, true);  // row_shr:2
    v = (v > t) ? v : t;
    t = __builtin_amdgcn_update_dpp(0, v, 0x114, 0xf, 0xf, true);  // row_shr:4
    v = (v > t) ? v : t;
    t = __builtin_amdgcn_update_dpp(0, v, 0x118, 0xf, 0xf, true);  // row_shr:8
    v = (v > t) ? v : t;
    t = __builtin_amdgcn_update_dpp(v, v, 0x142, 0xa, 0xf, false); // row_bcast:15
    v = (v > t) ? v : t;
    t = __builtin_amdgcn_update_dpp(v, v, 0x143, 0xc, 0xf, false); // row_bcast:31
    v = (v > t) ? v : t;
    return __builtin_amdgcn_readlane(v, 63);
}

// Branch-free insert of k into sorted (m1 >= m2 >= m3), 64-bit keys.
__device__ __forceinline__ void insert3(unsigned long long k,
    unsigned long long& m1, unsigned long long& m2, unsigned long long& m3) {
    const bool c1 = k > m1, c2 = k > m2, c3 = k > m3;
    m3 = c3 ? (c2 ? m2 : k) : m3;   // uses old m2
    m2 = c2 ? (c1 ? m1 : k) : m2;   // uses old m1
    m1 = c1 ? k : m1;
}

// Kernel 1: one 64-lane wave per row; 32 scores/lane in registers.
// Exact ordered top-20 (score desc, col asc on float-bit ties); writes base
// output adj*EPS (non-temporal) and winners[slice][row][rank] = col.
__global__ __launch_bounds__(256) void mask_topk_rows(
    const float* __restrict__ adj, const float* __restrict__ noise,
    float* __restrict__ out, unsigned short* __restrict__ winners)
{
    const int lane  = threadIdx.x & 63;
    const int wave  = threadIdx.x >> 6;
    const int row_g = (blockIdx.x << 2) + wave;     // 0..16383
    const int slice = row_g >> 11;
    const int row   = row_g & (NN - 1);
    const size_t base = ((size_t)slice * NN + row) * NN;
    const float* __restrict__ arow = adj + base;
    const float* __restrict__ nrow = noise + base;
    float* __restrict__ orow = out + base;

    float sc[32];
    unsigned long long m1 = 0ull, m2 = 0ull, m3 = 0ull;  // sorted top-3 keys
    const int lane4 = lane << 2;

    #pragma unroll
    for (int t = 0; t < 8; ++t) {
        const int col = t * 256 + lane4;
        const float4 av = *reinterpret_cast<const float4*>(arow + col);
        const float4 nv = *reinterpret_cast<const float4*>(nrow + col);
        vfloat4 ov;
        ov.x = av.x * 1e-7f; ov.y = av.y * 1e-7f;
        ov.z = av.z * 1e-7f; ov.w = av.w * 1e-7f;
        __builtin_nontemporal_store(ov, reinterpret_cast<vfloat4*>(orow + col));
        float s[4];
        {
            // must match numpy bitwise: separate mul + add, NO fma contraction
            #pragma clang fp contract(off)
            s[0] = fabsf(av.x) + nv.x * 0.01f;
            s[1] = fabsf(av.y) + nv.y * 0.01f;
            s[2] = fabsf(av.z) + nv.z * 0.01f;
            s[3] = fabsf(av.w) + nv.w * 0.01f;
        }
        #pragma unroll
        for (int c = 0; c < 4; ++c) {
            sc[t * 4 + c] = s[c];
            // score >= 0 -> bits compare monotonically. low32: 2047-col
            // (equal score -> larger key = smaller col). Keys unique per row.
            unsigned long long k =
                ((unsigned long long)__float_as_uint(s[c]) << 32) |
                (unsigned int)(NN - 1 - (col + c));
            insert3(k, m1, m2, m3);
        }
    }

    int cnt = 3;                 // valid entries in the per-lane cache
    unsigned int removed = 0;    // per-lane slot mask of extracted elements
    unsigned int mycol = 0;

    #pragma clang loop unroll(disable)
    for (int pass = 0; pass < KK; ++pass) {
        const int hs = (int)(unsigned int)(m1 >> 32);     // score bits (>=0)
        const int smax = wave_max_i32(hs);                // global max score
        const bool tied = (hs == smax);
        const unsigned long long ball = __ballot(tied);
        unsigned int col;
        bool iwin;
        if (__popcll(ball) == 1) {
            // fast path: unique score owner -- no tie-break reduce needed
            const int wl = __ffsll((long long)ball) - 1;  // SGPR-uniform lane
            const unsigned int wlo = (unsigned int)
                __builtin_amdgcn_readlane((int)(unsigned int)m1, wl);
            col = (NN - 1) - wlo;
            iwin = (lane == wl);
        } else {
            // exact tie on score bits across lanes: pick smallest col
            const int lo = tied ? (int)(unsigned int)m1 : 0;  // 2047-col
            const int tmax = wave_max_i32(lo);
            col = (NN - 1) - (unsigned int)tmax;
            iwin = tied && ((int)(unsigned int)m1 == tmax);
        }
        if (lane == pass) mycol = col;
        if (iwin) {
            const int slot = ((col >> 8) << 2) | (col & 3);
            removed |= (1u << slot);
            m1 = m2; m2 = m3; m3 = 0ull;
            if (--cnt == 0) {
                // rare (~0.3/row): rebuild top-3 of non-removed elements
                m1 = 0ull; m2 = 0ull; m3 = 0ull;
                #pragma unroll
                for (int ss = 0; ss < 32; ++ss) {
                    if (!((removed >> ss) & 1u)) {
                        const int c2 = ((ss >> 2) << 8) + lane4 + (ss & 3);
                        unsigned long long k =
                            ((unsigned long long)__float_as_uint(sc[ss]) << 32) |
                            (unsigned int)(NN - 1 - c2);
                        insert3(k, m1, m2, m3);
                    }
                }
                cnt = 3;
            }
        }
    }

    if (lane < KK) {
        winners[((size_t)slice * NN + row) * KK + lane] = (unsigned short)mycol;
    }
}

// Kernel 2: for each (slice,row,rank): col = winners[...];
// out[slice][col][rank] = adj*(1+EPS). Duplicate (col,rank) across rows
// write identical values -> benign race.
__global__ __launch_bounds__(256) void mask_boost(
    const float* __restrict__ adj, float* __restrict__ out,
    const unsigned short* __restrict__ winners)
{
    const int idx = blockIdx.x * 256 + threadIdx.x;
    if (idx >= NSLICE * NN * KK) return;
    const int rank  = idx % KK;
    const int slice = idx / (KK * NN);
    const int col = winners[idx];
    const size_t off = ((size_t)slice * NN + col) * NN + rank;
    out[off] = adj[off] * (1.0f + 1e-7f);
}

extern "C" void kernel_launch(void* const* d_in, const int* in_sizes, int n_in,
                              void* d_out, int out_size, void* d_ws, size_t ws_size,
                              hipStream_t stream) {
    const float* adj   = (const float*)d_in[0];
    const float* noise = (const float*)d_in[1];
    float* out = (float*)d_out;
    unsigned short* winners = (unsigned short*)d_ws;  // 8*2048*20*2B = 640 KiB

    const int rows = NSLICE * NN;                 // 16384 rows, 4 per block
    mask_topk_rows<<<rows / 4, 256, 0, stream>>>(adj, noise, out, winners);

    const int total = NSLICE * NN * KK;           // 327,680
    mask_boost<<<(total + 255) / 256, 256, 0, stream>>>(adj, out, winners);
}

// Round 4
// 80.224 us; speedup vs baseline: 1.3153x; 1.0095x over previous
//
#include <hip/hip_runtime.h>
#include <stdint.h>

#define NN 2048
#define KK 20
#define NSLICE 8   // L*B = 2*4

typedef float vfloat4 __attribute__((ext_vector_type(4)));

// Wave-wide max of a nonnegative int, result broadcast (SGPR). Pure VALU DPP.
__device__ __forceinline__ int wave_max_i32(int v) {
    int t;
    t = __builtin_amdgcn_update_dpp(0, v, 0x111, 0xf, 0xf, true);  // row_shr:1
    v = (v > t) ? v : t;
    t = __builtin_amdgcn_update_dpp(0, v, 0x112, 0xf, 0xf, true);  // row_shr:2
    v = (v > t) ? v : t;
    t = __builtin_amdgcn_update_dpp(0, v, 0x114, 0xf, 0xf, true);  // row_shr:4
    v = (v > t) ? v : t;
    t = __builtin_amdgcn_update_dpp(0, v, 0x118, 0xf, 0xf, true);  // row_shr:8
    v = (v > t) ? v : t;
    t = __builtin_amdgcn_update_dpp(v, v, 0x142, 0xa, 0xf, false); // row_bcast:15
    v = (v > t) ? v : t;
    t = __builtin_amdgcn_update_dpp(v, v, 0x143, 0xc, 0xf, false); // row_bcast:31
    v = (v > t) ? v : t;
    return __builtin_amdgcn_readlane(v, 63);
}

// Branch-free insert of k into sorted (m1 >= m2 >= m3), 64-bit keys.
__device__ __forceinline__ void insert3(unsigned long long k,
    unsigned long long& m1, unsigned long long& m2, unsigned long long& m3) {
    const bool c1 = k > m1, c2 = k > m2, c3 = k > m3;
    m3 = c3 ? (c2 ? m2 : k) : m3;   // uses old m2
    m2 = c2 ? (c1 ? m1 : k) : m2;   // uses old m1
    m1 = c1 ? k : m1;
}

// Kernel 1: one 64-lane wave per row; 32 scores/lane in registers.
// Exact ordered top-20 (score desc, col asc on float-bit ties); writes base
// output adj*EPS (non-temporal) and winners[slice][row][rank] = col.
__global__ __launch_bounds__(256) void mask_topk_rows(
    const float* __restrict__ adj, const float* __restrict__ noise,
    float* __restrict__ out, unsigned short* __restrict__ winners)
{
    const int lane  = threadIdx.x & 63;
    const int wave  = threadIdx.x >> 6;
    const int row_g = (blockIdx.x << 2) + wave;     // 0..16383
    const int slice = row_g >> 11;
    const int row   = row_g & (NN - 1);
    const size_t base = ((size_t)slice * NN + row) * NN;
    const float* __restrict__ arow = adj + base;
    const float* __restrict__ nrow = noise + base;
    float* __restrict__ orow = out + base;

    const int lane4 = lane << 2;

    // ---- Issue ALL 16 row loads up front: MLP = 16 per wave ----
    float4 av[8], nv[8];
    #pragma unroll
    for (int t = 0; t < 8; ++t) {
        const int col = t * 256 + lane4;
        av[t] = *reinterpret_cast<const float4*>(arow + col);
        nv[t] = *reinterpret_cast<const float4*>(nrow + col);
    }
    // Keep the scheduler from sinking loads back into the compute loop
    // (it would do so to save VGPRs, destroying memory-level parallelism).
    __builtin_amdgcn_sched_barrier(0);

    float sc[32];
    unsigned long long m1 = 0ull, m2 = 0ull, m3 = 0ull;  // sorted top-3 keys

    #pragma unroll
    for (int t = 0; t < 8; ++t) {
        const int col = t * 256 + lane4;
        vfloat4 ov;
        ov.x = av[t].x * 1e-7f; ov.y = av[t].y * 1e-7f;
        ov.z = av[t].z * 1e-7f; ov.w = av[t].w * 1e-7f;
        __builtin_nontemporal_store(ov, reinterpret_cast<vfloat4*>(orow + col));
        float s[4];
        {
            // must match numpy bitwise: separate mul + add, NO fma contraction
            #pragma clang fp contract(off)
            s[0] = fabsf(av[t].x) + nv[t].x * 0.01f;
            s[1] = fabsf(av[t].y) + nv[t].y * 0.01f;
            s[2] = fabsf(av[t].z) + nv[t].z * 0.01f;
            s[3] = fabsf(av[t].w) + nv[t].w * 0.01f;
        }
        #pragma unroll
        for (int c = 0; c < 4; ++c) {
            sc[t * 4 + c] = s[c];
            // score >= 0 -> bits compare monotonically. low32: 2047-col
            // (equal score -> larger key = smaller col). Keys unique per row.
            unsigned long long k =
                ((unsigned long long)__float_as_uint(s[c]) << 32) |
                (unsigned int)(NN - 1 - (col + c));
            insert3(k, m1, m2, m3);
        }
    }

    int cnt = 3;                 // valid entries in the per-lane cache
    unsigned int removed = 0;    // per-lane slot mask of extracted elements
    unsigned int mycol = 0;

    #pragma clang loop unroll(disable)
    for (int pass = 0; pass < KK; ++pass) {
        const int hs = (int)(unsigned int)(m1 >> 32);     // score bits (>=0)
        const int smax = wave_max_i32(hs);                // global max score
        const bool tied = (hs == smax);
        const unsigned long long ball = __ballot(tied);
        unsigned int col;
        bool iwin;
        if (__popcll(ball) == 1) {
            // fast path: unique score owner -- no tie-break reduce needed
            const int wl = __ffsll((long long)ball) - 1;  // SGPR-uniform lane
            const unsigned int wlo = (unsigned int)
                __builtin_amdgcn_readlane((int)(unsigned int)m1, wl);
            col = (NN - 1) - wlo;
            iwin = (lane == wl);
        } else {
            // exact tie on score bits across lanes: pick smallest col
            const int lo = tied ? (int)(unsigned int)m1 : 0;  // 2047-col
            const int tmax = wave_max_i32(lo);
            col = (NN - 1) - (unsigned int)tmax;
            iwin = tied && ((int)(unsigned int)m1 == tmax);
        }
        if (lane == pass) mycol = col;
        if (iwin) {
            const int slot = ((col >> 8) << 2) | (col & 3);
            removed |= (1u << slot);
            m1 = m2; m2 = m3; m3 = 0ull;
            if (--cnt == 0) {
                // rare (~0.3/row): rebuild top-3 of non-removed elements
                m1 = 0ull; m2 = 0ull; m3 = 0ull;
                #pragma unroll
                for (int ss = 0; ss < 32; ++ss) {
                    if (!((removed >> ss) & 1u)) {
                        const int c2 = ((ss >> 2) << 8) + lane4 + (ss & 3);
                        unsigned long long k =
                            ((unsigned long long)__float_as_uint(sc[ss]) << 32) |
                            (unsigned int)(NN - 1 - c2);
                        insert3(k, m1, m2, m3);
                    }
                }
                cnt = 3;
            }
        }
    }

    if (lane < KK) {
        winners[((size_t)slice * NN + row) * KK + lane] = (unsigned short)mycol;
    }
}

// Kernel 2: for each (slice,row,rank): col = winners[...];
// out[slice][col][rank] = adj*(1+EPS). Duplicate (col,rank) across rows
// write identical values -> benign race.
__global__ __launch_bounds__(256) void mask_boost(
    const float* __restrict__ adj, float* __restrict__ out,
    const unsigned short* __restrict__ winners)
{
    const int idx = blockIdx.x * 256 + threadIdx.x;
    if (idx >= NSLICE * NN * KK) return;
    const int rank  = idx % KK;
    const int slice = idx / (KK * NN);
    const int col = winners[idx];
    const size_t off = ((size_t)slice * NN + col) * NN + rank;
    out[off] = adj[off] * (1.0f + 1e-7f);
}

extern "C" void kernel_launch(void* const* d_in, const int* in_sizes, int n_in,
                              void* d_out, int out_size, void* d_ws, size_t ws_size,
                              hipStream_t stream) {
    const float* adj   = (const float*)d_in[0];
    const float* noise = (const float*)d_in[1];
    float* out = (float*)d_out;
    unsigned short* winners = (unsigned short*)d_ws;  // 8*2048*20*2B = 640 KiB

    const int rows = NSLICE * NN;                 // 16384 rows, 4 per block
    mask_topk_rows<<<rows / 4, 256, 0, stream>>>(adj, noise, out, winners);

    const int total = NSLICE * NN * KK;           // 327,680
    mask_boost<<<(total + 255) / 256, 256, 0, stream>>>(adj, out, winners);
}

// Round 5
// 79.149 us; speedup vs baseline: 1.3331x; 1.0136x over previous
//
#include <hip/hip_runtime.h>
#include <stdint.h>

#define NN 2048
#define KK 20
#define NSLICE 8   // L*B = 2*4

typedef float vfloat4 __attribute__((ext_vector_type(4)));

// Wave-wide max of a nonnegative int, result broadcast (SGPR). Pure VALU DPP.
__device__ __forceinline__ int wave_max_i32(int v) {
    int t;
    t = __builtin_amdgcn_update_dpp(0, v, 0x111, 0xf, 0xf, true);  // row_shr:1
    v = (v > t) ? v : t;
    t = __builtin_amdgcn_update_dpp(0, v, 0x112, 0xf, 0xf, true);  // row_shr:2
    v = (v > t) ? v : t;
    t = __builtin_amdgcn_update_dpp(0, v, 0x114, 0xf, 0xf, true);  // row_shr:4
    v = (v > t) ? v : t;
    t = __builtin_amdgcn_update_dpp(0, v, 0x118, 0xf, 0xf, true);  // row_shr:8
    v = (v > t) ? v : t;
    t = __builtin_amdgcn_update_dpp(v, v, 0x142, 0xa, 0xf, false); // row_bcast:15
    v = (v > t) ? v : t;
    t = __builtin_amdgcn_update_dpp(v, v, 0x143, 0xc, 0xf, false); // row_bcast:31
    v = (v > t) ? v : t;
    return __builtin_amdgcn_readlane(v, 63);
}

// Branch-free insert of k into sorted (m1 >= m2 >= m3), 64-bit keys.
__device__ __forceinline__ void insert3(unsigned long long k,
    unsigned long long& m1, unsigned long long& m2, unsigned long long& m3) {
    const bool c1 = k > m1, c2 = k > m2, c3 = k > m3;
    m3 = c3 ? (c2 ? m2 : k) : m3;   // uses old m2
    m2 = c2 ? (c1 ? m1 : k) : m2;   // uses old m1
    m1 = c1 ? k : m1;
}

// Per-tile consume: wait for this tile's two loads (14-t accounts for the t
// nontemporal stores already in the vmcnt FIFO), fence the scheduler (rule
// #18: reg-only uses hoist past asm waitcnt without sched_barrier), then
// write base output and feed scores into the per-lane top-3 cache.
#define TILE(t, vm) do {                                                     \
    asm volatile("s_waitcnt vmcnt(" #vm ")" ::: "memory");                   \
    __builtin_amdgcn_sched_barrier(0);                                       \
    const int col = (t) * 256 + lane4;                                       \
    vfloat4 ov = av[t] * 1e-7f;                                              \
    __builtin_nontemporal_store(ov, reinterpret_cast<vfloat4*>(orow + col)); \
    float s[4];                                                              \
    {                                                                        \
        _Pragma("clang fp contract(off)")                                    \
        s[0] = fabsf(av[t].x) + nv[t].x * 0.01f;                             \
        s[1] = fabsf(av[t].y) + nv[t].y * 0.01f;                             \
        s[2] = fabsf(av[t].z) + nv[t].z * 0.01f;                             \
        s[3] = fabsf(av[t].w) + nv[t].w * 0.01f;                             \
    }                                                                        \
    _Pragma("unroll")                                                        \
    for (int c = 0; c < 4; ++c) {                                            \
        sc[(t) * 4 + c] = s[c];                                              \
        unsigned long long k =                                               \
            ((unsigned long long)__float_as_uint(s[c]) << 32) |              \
            (unsigned int)(NN - 1 - (col + c));                              \
        insert3(k, m1, m2, m3);                                              \
    }                                                                        \
} while (0)

// Kernel 1: one 64-lane wave per row; 32 scores/lane in registers.
// All 16 row loads issued up-front via inline asm (MLP=16, cannot be sunk),
// consumed under counted vmcnt. Exact ordered top-20 per row; writes base
// output adj*EPS (non-temporal) and winners[slice][row][rank] = col.
__global__ __launch_bounds__(256) void mask_topk_rows(
    const float* __restrict__ adj, const float* __restrict__ noise,
    float* __restrict__ out, unsigned short* __restrict__ winners)
{
    const int lane  = threadIdx.x & 63;
    const int wave  = threadIdx.x >> 6;
    const int row_g = (blockIdx.x << 2) + wave;     // 0..16383
    const int slice = row_g >> 11;
    const int row   = row_g & (NN - 1);
    const size_t base = ((size_t)slice * NN + row) * NN;
    const float* __restrict__ arow = adj + base;
    const float* __restrict__ nrow = noise + base;
    float* __restrict__ orow = out + base;

    const int lane4 = lane << 2;

    // ---- Issue ALL 16 loads via volatile asm: stays at top, 16 in flight ----
    vfloat4 av[8], nv[8];
    #pragma unroll
    for (int t = 0; t < 8; ++t) {
        asm volatile("global_load_dwordx4 %0, %1, off"
                     : "=v"(av[t]) : "v"(arow + t * 256 + lane4));
        asm volatile("global_load_dwordx4 %0, %1, off"
                     : "=v"(nv[t]) : "v"(nrow + t * 256 + lane4));
    }
    __builtin_amdgcn_sched_barrier(0);

    float sc[32];
    unsigned long long m1 = 0ull, m2 = 0ull, m3 = 0ull;  // sorted top-3 keys

    TILE(0, 14); TILE(1, 13); TILE(2, 12); TILE(3, 11);
    TILE(4, 10); TILE(5,  9); TILE(6,  8); TILE(7,  7);

    int cnt = 3;                 // valid entries in the per-lane cache
    unsigned int removed = 0;    // per-lane slot mask of extracted elements
    unsigned int mycol = 0;

    #pragma clang loop unroll(disable)
    for (int pass = 0; pass < KK; ++pass) {
        const int hs = (int)(unsigned int)(m1 >> 32);     // score bits (>=0)
        const int smax = wave_max_i32(hs);                // global max score
        const bool tied = (hs == smax);
        const unsigned long long ball = __ballot(tied);
        unsigned int col;
        bool iwin;
        if (__popcll(ball) == 1) {
            // fast path: unique score owner -- no tie-break reduce needed
            const int wl = __ffsll((long long)ball) - 1;  // SGPR-uniform lane
            const unsigned int wlo = (unsigned int)
                __builtin_amdgcn_readlane((int)(unsigned int)m1, wl);
            col = (NN - 1) - wlo;
            iwin = (lane == wl);
        } else {
            // exact tie on score bits across lanes: pick smallest col
            const int lo = tied ? (int)(unsigned int)m1 : 0;  // 2047-col
            const int tmax = wave_max_i32(lo);
            col = (NN - 1) - (unsigned int)tmax;
            iwin = tied && ((int)(unsigned int)m1 == tmax);
        }
        if (lane == pass) mycol = col;
        if (iwin) {
            const int slot = ((col >> 8) << 2) | (col & 3);
            removed |= (1u << slot);
            m1 = m2; m2 = m3; m3 = 0ull;
            if (--cnt == 0) {
                // rare (~0.3/row): rebuild top-3 of non-removed elements
                m1 = 0ull; m2 = 0ull; m3 = 0ull;
                #pragma unroll
                for (int ss = 0; ss < 32; ++ss) {
                    if (!((removed >> ss) & 1u)) {
                        const int c2 = ((ss >> 2) << 8) + lane4 + (ss & 3);
                        unsigned long long k =
                            ((unsigned long long)__float_as_uint(sc[ss]) << 32) |
                            (unsigned int)(NN - 1 - c2);
                        insert3(k, m1, m2, m3);
                    }
                }
                cnt = 3;
            }
        }
    }

    if (lane < KK) {
        winners[((size_t)slice * NN + row) * KK + lane] = (unsigned short)mycol;
    }
}

// Kernel 2: for each (slice,row,rank): col = winners[...];
// out[slice][col][rank] = adj*(1+EPS). Duplicate (col,rank) across rows
// write identical values -> benign race.
__global__ __launch_bounds__(256) void mask_boost(
    const float* __restrict__ adj, float* __restrict__ out,
    const unsigned short* __restrict__ winners)
{
    const int idx = blockIdx.x * 256 + threadIdx.x;
    if (idx >= NSLICE * NN * KK) return;
    const int rank  = idx % KK;
    const int slice = idx / (KK * NN);
    const int col = winners[idx];
    const size_t off = ((size_t)slice * NN + col) * NN + rank;
    out[off] = adj[off] * (1.0f + 1e-7f);
}

extern "C" void kernel_launch(void* const* d_in, const int* in_sizes, int n_in,
                              void* d_out, int out_size, void* d_ws, size_t ws_size,
                              hipStream_t stream) {
    const float* adj   = (const float*)d_in[0];
    const float* noise = (const float*)d_in[1];
    float* out = (float*)d_out;
    unsigned short* winners = (unsigned short*)d_ws;  // 8*2048*20*2B = 640 KiB

    const int rows = NSLICE * NN;                 // 16384 rows, 4 per block
    mask_topk_rows<<<rows / 4, 256, 0, stream>>>(adj, noise, out, winners);

    const int total = NSLICE * NN * KK;           // 327,680
    mask_boost<<<(total + 255) / 256, 256, 0, stream>>>(adj, out, winners);
}